// Round 14
// baseline (274.784 us; speedup 1.0000x reference)
//
#include <hip/hip_runtime.h>
#include <math.h>

#define N 512
#define BATCH 128
#define EPS 1e-8f
#define TPB 1024         // 16 waves
#define NW 16
#define KP 320           // max kp for direct LDS path (kp mult of 32)
#define LN2 0.69314718055994530942f
#define SPLIT 160        // zcase split (multiple of 32)
#define GSTR 160         // G LDS row stride in halves (320B rows, 16B-mult)
#define SLD2 356         // S slab row stride (floats)
#define SLAB_BYTES (352 * SLD2 * 4)

typedef _Float16 f16;
typedef _Float16 f16x8 __attribute__((ext_vector_type(8)));
typedef float f32x4 __attribute__((ext_vector_type(4)));

// packed fp16 triangle: row r starts 16B-aligned, length rup(r+1,8)
__device__ __forceinline__ int lh_base(int r) {
    const int a = r >> 3, b = r & 7;
    return 8 * (a + 1) * (4 * a + b);
}

// arena (bytes). tri regions: MODE0 tri(320)=104960, MODE1 tri(160)=26880,
// MODE2 tri(352)=126720 — all < DW_OFF. G only in MODE1: 26880+112640=139520.
#define G1_OFF   26880
#define DW_OFF   139520   // [32][40] f16: diag-S block, then overlaid by W (inverse)
#define SCR_OFF  142080   // 15 tile-wave slots x [16][40] f16 = 1280 B each
#define ARENA_SZ 161280

__device__ __forceinline__ float rdl(float v, int l) {
    return __builtin_bit_cast(float,
        __builtin_amdgcn_readlane(__builtin_bit_cast(int, v), l));
}

__device__ __forceinline__ void tri_map(int e, int* r_out, int* c_out) {
    int rr = (int)((sqrtf(8.0f * (float)e + 1.0f) - 1.0f) * 0.5f);
    while ((((rr + 1) * (rr + 2)) >> 1) <= e) ++rr;
    while (((rr * (rr + 1)) >> 1) > e) --rr;
    *r_out = rr;
    *c_out = e - ((rr * (rr + 1)) >> 1);
}

// ---------- L = B^T B + EPS*I : 64x64 register-tiled ----------
__global__ __launch_bounds__(256) void compute_L(const float* __restrict__ B,
                                                 float* __restrict__ L) {
    const int r0 = blockIdx.x * 64, c0 = blockIdx.y * 64;
    const int tx = threadIdx.x & 15, ty = threadIdx.x >> 4;
    __shared__ float Bi[16][64];
    __shared__ float Bj[16][64];
    float acc[4][4] = {};
    for (int k0 = 0; k0 < N; k0 += 16) {
#pragma unroll
        for (int q = 0; q < 4; ++q) {
            const int e = threadIdx.x + q * 256;
            const int kr = e >> 6, cc = e & 63;
            Bi[kr][cc] = B[(k0 + kr) * N + r0 + cc];
            Bj[kr][cc] = B[(k0 + kr) * N + c0 + cc];
        }
        __syncthreads();
#pragma unroll
        for (int kq = 0; kq < 16; ++kq) {
            float a[4], b[4];
#pragma unroll
            for (int q = 0; q < 4; ++q) {
                a[q] = Bi[kq][ty * 4 + q];
                b[q] = Bj[kq][tx * 4 + q];
            }
#pragma unroll
            for (int i = 0; i < 4; ++i)
#pragma unroll
                for (int j = 0; j < 4; ++j) acc[i][j] = fmaf(a[i], b[j], acc[i][j]);
        }
        __syncthreads();
    }
#pragma unroll
    for (int i = 0; i < 4; ++i) {
        const int r = r0 + ty * 4 + i;
        f32x4 v;
#pragma unroll
        for (int j = 0; j < 4; ++j) {
            const int c = c0 + tx * 4 + j;
            v[j] = acc[i][j] + ((r == c) ? EPS : 0.0f);
        }
        *(f32x4*)(&L[r * N + c0 + tx * 4]) = v;
    }
}

// gather: MODE 0/1 from L via idx (+add1 diag); MODE 2 from S slab (lower tri)
template <int MODE>
__device__ __forceinline__ float gath(const float* __restrict__ L,
                                      const float* __restrict__ S, const short* idx,
                                      int k, bool add1, int gr, int gc) {
    if constexpr (MODE <= 1) {
        if (gr < k && gc < k) {
            float v = L[(int)idx[gr] * N + (int)idx[gc]];
            if (add1 && gr == gc) v += 1.0f;
            return v;
        }
        return (gr == gc) ? 1.0f : 0.0f;
    } else {
        if (gr < k && gc < k) {
            const int r2 = gr > gc ? gr : gc, c2 = gr > gc ? gc : gr;
            return S[r2 * SLD2 + c2];
        }
        return (gr == gc) ? 1.0f : 0.0f;
    }
}

// ---------- 32-col-panel left-looking Cholesky ----------
// Per panel: wave 0 builds the full 32x32 diag Schur block, factors it in ONE
// 32-step register chain (rows per lane, readlane broadcasts) producing L00
// and W = L00^{-1} as a by-product. Tile waves do their kk-chains + stage a
// full K=32 S-frag. After barrier 1, X = S_tile · W^T in exactly 2 MFMAs.
// MODE 0: all rows in Lh. MODE 1: rows >= SPLIT in G. MODE 2: source = S slab.
template <int MODE>
__device__ float cholp(char* arena, const float* __restrict__ S,
                       const float* __restrict__ L, const short* idx,
                       int k, int rows, int ncols, bool add1) {
    const int tid = threadIdx.x;
    const int lane = tid & 63, wv = tid >> 6;
    f16* Lh = (f16*)arena;
    f16* Gl = (f16*)(arena + G1_OFF);
    f16* DW = (f16*)(arena + DW_OFF);                     // [32][40]
    f16* scrw = (f16*)(arena + SCR_OFF) + (wv > 0 ? (wv - 1) * 640 : 0);  // [16][40]
    const int frow = lane & 15, koff = (lane >> 4) * 8;
    const int crow = (lane >> 4) * 4, ccol = lane & 15;
    const f32x4 zz = {0.f, 0.f, 0.f, 0.f};

    float lg2 = 0.0f;
    for (int jb = 0; jb < ncols; jb += 32) {
        const int nkk = jb >> 5;
        const int nbelow = (rows - jb - 32) >> 4;

        bool val_[2] = {false, false};
        int r0_[2] = {0, 0};
        f16x8 afs_[2] = {};

        if (wv == 0) {
            // ---- (b) wave 0: full 32x32 diag block
            f32x4 g00 = zz, g10 = zz, g11 = zz;
#pragma unroll
            for (int q = 0; q < 4; ++q) {
                g00[q] = gath<MODE>(L, S, idx, k, add1, jb + crow + q, jb + ccol);
                g10[q] = gath<MODE>(L, S, idx, k, add1, jb + 16 + crow + q, jb + ccol);
                g11[q] = gath<MODE>(L, S, idx, k, add1, jb + 16 + crow + q, jb + 16 + ccol);
            }
            const int bF0 = lh_base(jb + frow) + koff;
            const int bF1 = lh_base(jb + 16 + frow) + koff;
            f32x4 a00 = zz, a10 = zz, a11 = zz;
            for (int cg = 0; cg < nkk; cg += 4) {
                f16x8 F0_[4], F1_[4];
#pragma unroll
                for (int u = 0; u < 4; ++u) {
                    const int c = cg + u;
                    const bool ok = c < nkk;
                    F0_[u] = ok ? *(const f16x8*)(&Lh[bF0 + (c << 5)]) : (f16x8){};
                    F1_[u] = ok ? *(const f16x8*)(&Lh[bF1 + (c << 5)]) : (f16x8){};
                }
#pragma unroll
                for (int u = 0; u < 4; ++u)
                    if (cg + u < nkk) {
                        a00 = __builtin_amdgcn_mfma_f32_16x16x32_f16(F0_[u], F0_[u], a00, 0, 0, 0);
                        a10 = __builtin_amdgcn_mfma_f32_16x16x32_f16(F1_[u], F0_[u], a10, 0, 0, 0);
                        a11 = __builtin_amdgcn_mfma_f32_16x16x32_f16(F1_[u], F1_[u], a11, 0, 0, 0);
                    }
            }
            // dump S block (lower blocks) to DW
#pragma unroll
            for (int q = 0; q < 4; ++q) {
                DW[(crow + q) * 40 + ccol] = (f16)(g00[q] - a00[q]);
                DW[(16 + crow + q) * 40 + ccol] = (f16)(g10[q] - a10[q]);
                DW[(16 + crow + q) * 40 + 16 + ccol] = (f16)(g11[q] - a11[q]);
            }
            // row-per-lane read (same wave, in-order)
            const int r = lane & 31;
            float row[32], w[32];
#pragma unroll
            for (int m = 0; m < 4; ++m) {
                const f16x8 hv = *(const f16x8*)(&DW[r * 40 + 8 * m]);
#pragma unroll
                for (int e = 0; e < 8; ++e) row[8 * m + e] = (float)hv[e];
            }
#pragma unroll
            for (int c = 0; c < 32; ++c) w[c] = (c == r) ? 1.0f : 0.0f;
            // 32-step factor + inverse
#pragma unroll
            for (int j = 0; j < 32; ++j) {
                const float piv = rdl(row[j], j);
                lg2 += __log2f(piv);
                const float irs = rsqrtf(piv);
                row[j] *= irs;
                w[j] *= irs;
#pragma unroll
                for (int cc = j + 1; cc < 32; ++cc) {
                    const float s2 = rdl(row[j], cc);
                    row[cc] = fmaf(-row[j], s2, row[cc]);
                    w[cc] = fmaf(-s2, w[j], w[cc]);
                }
            }
            if (lane < 32) {
                // zero-mask upper, publish factor rows jb+lane (masked chunks)
                const int nch = (lane >> 3) + 1;
#pragma unroll
                for (int m = 0; m < 4; ++m) {
                    if (m < nch) {
                        f16x8 hv;
#pragma unroll
                        for (int e = 0; e < 8; ++e) {
                            const int c = 8 * m + e;
                            hv[e] = (f16)((c > lane) ? 0.0f : row[c]);
                        }
                        *(f16x8*)(&Lh[lh_base(jb + lane) + jb + 8 * m]) = hv;
                    }
                }
                // publish W (overlays DW; DW dead after row-read)
#pragma unroll
                for (int i = 0; i < 32; ++i) DW[i * 40 + lane] = (f16)w[i];
            }
        } else {
            // ---- (a) tile waves: kk-chains for owned tiles, both col-halves
            bool isg_[2];
            int baseA_[2];
#pragma unroll
            for (int it = 0; it < 2; ++it) {
                const int tb = (wv - 1) + 15 * it;
                val_[it] = tb < nbelow;
                const int rr = jb + 32 + 16 * (val_[it] ? tb : 0);
                r0_[it] = rr;
                isg_[it] = (MODE == 1) && val_[it] && (rr >= SPLIT);
                baseA_[it] = isg_[it] ? ((rr - SPLIT + frow) * GSTR + koff)
                                      : (lh_base(rr + frow) + koff);
            }
            f32x4 g0_[2] = {zz, zz}, g1_[2] = {zz, zz};
#pragma unroll
            for (int it = 0; it < 2; ++it)
                if (val_[it]) {
#pragma unroll
                    for (int q = 0; q < 4; ++q) {
                        g0_[it][q] = gath<MODE>(L, S, idx, k, add1, r0_[it] + crow + q, jb + ccol);
                        g1_[it][q] = gath<MODE>(L, S, idx, k, add1, r0_[it] + crow + q, jb + 16 + ccol);
                    }
                }
            const int bB0 = lh_base(jb + frow) + koff;
            const int bB1 = lh_base(jb + 16 + frow) + koff;
            f32x4 ac0_[2] = {zz, zz}, ac1_[2] = {zz, zz};
            for (int cg = 0; cg < nkk; cg += 4) {
                f16x8 B0_[4], B1_[4], A_[4][2];
#pragma unroll
                for (int u = 0; u < 4; ++u) {
                    const int c = cg + u;
                    const bool ok = c < nkk;
                    const int kk = c << 5;
                    B0_[u] = ok ? *(const f16x8*)(&Lh[bB0 + kk]) : (f16x8){};
                    B1_[u] = ok ? *(const f16x8*)(&Lh[bB1 + kk]) : (f16x8){};
#pragma unroll
                    for (int it = 0; it < 2; ++it) {
                        f16x8 vv = {};
                        if (ok && val_[it])
                            vv = isg_[it] ? *(const f16x8*)(&Gl[baseA_[it] + kk])
                                          : *(const f16x8*)(&Lh[baseA_[it] + kk]);
                        A_[u][it] = vv;
                    }
                }
#pragma unroll
                for (int u = 0; u < 4; ++u)
                    if (cg + u < nkk) {
#pragma unroll
                        for (int it = 0; it < 2; ++it)
                            if (val_[it]) {
                                ac0_[it] = __builtin_amdgcn_mfma_f32_16x16x32_f16(
                                    A_[u][it], B0_[u], ac0_[it], 0, 0, 0);
                                ac1_[it] = __builtin_amdgcn_mfma_f32_16x16x32_f16(
                                    A_[u][it], B1_[u], ac1_[it], 0, 0, 0);
                            }
                    }
            }
            // stage full 16x32 S tile -> scr -> K=32 A-frag (same wave, in order)
#pragma unroll
            for (int it = 0; it < 2; ++it)
                if (val_[it]) {
#pragma unroll
                    for (int q = 0; q < 4; ++q) {
                        scrw[(crow + q) * 40 + ccol] = (f16)(g0_[it][q] - ac0_[it][q]);
                        scrw[(crow + q) * 40 + 16 + ccol] = (f16)(g1_[it][q] - ac1_[it][q]);
                    }
                    afs_[it] = *(const f16x8*)(&scrw[frow * 40 + koff]);
                }
        }
        __syncthreads();   // barrier 1: W + diag factor rows published

        // ---- (c) X = S_tile · W^T : two MFMAs per owned tile
        {
            const f16x8 bW0 = *(const f16x8*)(&DW[frow * 40 + koff]);
            const f16x8 bW1 = *(const f16x8*)(&DW[(16 + frow) * 40 + koff]);
#pragma unroll
            for (int it = 0; it < 2; ++it)
                if (val_[it]) {
                    const f32x4 x0 = __builtin_amdgcn_mfma_f32_16x16x32_f16(afs_[it], bW0, zz, 0, 0, 0);
                    const f32x4 x1 = __builtin_amdgcn_mfma_f32_16x16x32_f16(afs_[it], bW1, zz, 0, 0, 0);
#pragma unroll
                    for (int q = 0; q < 4; ++q) {
                        const int gr = r0_[it] + crow + q;
                        const f16 h0 = (f16)x0[q], h1 = (f16)x1[q];
                        if (MODE == 1 && gr >= SPLIT) {
                            Gl[(gr - SPLIT) * GSTR + jb + ccol] = h0;
                            Gl[(gr - SPLIT) * GSTR + jb + 16 + ccol] = h1;
                        } else {
                            Lh[lh_base(gr) + jb + ccol] = h0;
                            Lh[lh_base(gr) + jb + 16 + ccol] = h1;
                        }
                    }
                }
        }
        __syncthreads();   // barrier 2: factor cols jb..jb+31 published
    }
    return lg2;
}

// ---------- S = A22 - G·G^T, G in LDS; S (fp32) streamed to global ----------
__device__ void schur32(char* arena, float* __restrict__ S,
                        const float* __restrict__ L, const short* idx,
                        int k, int k2p, bool add1) {
    const int tid = threadIdx.x;
    const int lane = tid & 63, wv = tid >> 6;
    const f16* Gl = (const f16*)(arena + G1_OFF);
    const int frow = lane & 15, koff = (lane >> 4) * 8;
    const int crow = (lane >> 4) * 4, ccol = lane & 15;
    const int nt2 = k2p >> 4, TT = (nt2 * (nt2 + 1)) >> 1;
    for (int e = wv; e < TT; e += NW) {
        int R, C;
        tri_map(e, &R, &C);
        const int r0 = R << 4, c0 = C << 4;
        f32x4 g;
#pragma unroll
        for (int q = 0; q < 4; ++q) {
            const int gr = SPLIT + r0 + crow + q, gc = SPLIT + c0 + ccol;
            float v;
            if (gr < k && gc < k) {
                v = L[(int)idx[gr] * N + (int)idx[gc]];
                if (add1 && gr == gc) v += 1.0f;
            } else v = (gr == gc) ? 1.0f : 0.0f;
            g[q] = v;
        }
        const int ba = (r0 + frow) * GSTR + koff, bb = (c0 + frow) * GSTR + koff;
        f32x4 acc = {0.f, 0.f, 0.f, 0.f};
#pragma unroll
        for (int c = 0; c < SPLIT / 32; ++c) {
            const f16x8 A = *(const f16x8*)(&Gl[ba + (c << 5)]);
            const f16x8 B = *(const f16x8*)(&Gl[bb + (c << 5)]);
            acc = __builtin_amdgcn_mfma_f32_16x16x32_f16(A, B, acc, 0, 0, 0);
        }
#pragma unroll
        for (int q = 0; q < 4; ++q)
            S[(r0 + crow + q) * SLD2 + c0 + ccol] = g[q] - acc[q];
    }
}

// ---------- one block per batch item; block BATCH = logdet(L+I) ----------
__global__ __launch_bounds__(TPB, 4) void chol_all(const int* __restrict__ x,
                                                   const float* __restrict__ L,
                                                   char* __restrict__ slabs, int nslabs,
                                                   float* __restrict__ logs) {
    const int b = blockIdx.x;
    const int tid = threadIdx.x;
    const int lane = tid & 63, wv = tid >> 6;
    __shared__ __align__(16) char arena[ARENA_SZ];
    __shared__ short idx[N];
    __shared__ int wcnt[NW];

    const bool zc = (b == BATCH);
    const bool inx = tid < N;
    const bool act = zc ? inx : (inx && x[(size_t)b * N + tid] != 0);
    const unsigned long long m = __ballot(act);
    if (lane == 0) wcnt[wv] = __popcll(m);
    __syncthreads();
    int off = 0, ktot = 0;
    for (int q = 0; q < NW; ++q) {
        if (q < wv) off += wcnt[q];
        ktot += wcnt[q];
    }
    if (act) idx[off + __popcll(m & ((1ULL << lane) - 1ULL))] = (short)tid;
    __syncthreads();

    const int k = ktot;
    const int kp = (k + 31) & ~31;

    float lg2;
    if (!zc && kp <= KP) {
        lg2 = cholp<0>(arena, nullptr, L, idx, k, kp, kp, false);
    } else {
        const int si = zc ? 0 : (nslabs > 1 ? 1 + (b % (nslabs - 1)) : 0);
        float* S = (float*)(slabs + (size_t)si * SLAB_BYTES);
        const int k2 = k - SPLIT, k2p = kp - SPLIT;
        lg2 = cholp<1>(arena, nullptr, L, idx, k, kp, SPLIT, zc);
        schur32(arena, S, L, idx, k, k2p, zc);
        __syncthreads();   // all G reads done before stage2 overwrites the arena
        lg2 += cholp<2>(arena, S, L, idx, k2, k2p, k2p, false);
    }
    if (tid == 0) logs[b] = lg2 * LN2;
}

__global__ void finalize(const float* __restrict__ logs, float* __restrict__ out) {
    const int i = threadIdx.x;
    out[i] = logs[i] - logs[BATCH];
}

extern "C" void kernel_launch(void* const* d_in, const int* in_sizes, int n_in,
                              void* d_out, int out_size, void* d_ws, size_t ws_size,
                              hipStream_t stream) {
    const int* x = (const int*)d_in[0];
    const float* B = (const float*)d_in[1];
    float* out = (float*)d_out;

    char* ws = (char*)d_ws;
    const size_t L_bytes = (size_t)N * N * 4;  // 1 MB
    float* L = (float*)ws;
    float* logs = (float*)(ws + L_bytes);
    const size_t head = L_bytes + 4096;
    char* slabs = ws + head;
    int nslabs = (ws_size > head) ? (int)((ws_size - head) / SLAB_BYTES) : 1;
    if (nslabs < 1) nslabs = 1;
    if (nslabs > 9) nslabs = 9;

    compute_L<<<dim3(8, 8), 256, 0, stream>>>(B, L);
    chol_all<<<BATCH + 1, TPB, 0, stream>>>(x, L, slabs, nslabs, logs);
    finalize<<<1, BATCH, 0, stream>>>(logs, out);
}

// Round 15
// 159.332 us; speedup vs baseline: 1.7246x; 1.7246x over previous
//
#include <hip/hip_runtime.h>
#include <math.h>

#define N 512
#define BATCH 128
#define EPS 1e-8f
#define TPB 1024         // 16 waves
#define NW 16
#define KP 304           // max kp for direct LDS path
#define LN2 0.69314718055994530942f
#define SPLIT 160        // zcase split (multiple of 32)
#define GSTR 160         // G LDS row stride in halves
#define SLD2 356         // S slab row stride (floats)
#define SLAB_BYTES (352 * SLD2 * 4)

typedef _Float16 f16;
typedef _Float16 f16x8 __attribute__((ext_vector_type(8)));
typedef float f32x4 __attribute__((ext_vector_type(4)));

// packed fp16 triangle: row r starts 16B-aligned, length rup(r+1,8)
__device__ __forceinline__ int lh_base(int r) {
    const int a = r >> 3, b = r & 7;
    return 8 * (a + 1) * (4 * a + b);
}

// arena layout (bytes):
// MODE0: Lh tri(304)=94848 | scr 16x1152 @94848 | M @113280 (end 115840)
// MODE1: Lh tri(160)=26880 | G [352][GSTR] @26880..139520 | scr @139520 | M @157952
// MODE2: Lh tri(352)=126720 | scr @126720 | M @145152 (end 147712)
#define G1_OFF   26880
#define SCR0_OFF 94848
#define M0_OFF   113280
#define SCR1_OFF 139520
#define M1_OFF   157952
#define SCR2_OFF 126720
#define M2_OFF   145152
#define ARENA_SZ 160512

__device__ __forceinline__ float rdl(float v, int l) {
    return __builtin_bit_cast(float,
        __builtin_amdgcn_readlane(__builtin_bit_cast(int, v), l));
}

__device__ __forceinline__ void tri_map(int e, int* r_out, int* c_out) {
    int rr = (int)((sqrtf(8.0f * (float)e + 1.0f) - 1.0f) * 0.5f);
    while ((((rr + 1) * (rr + 2)) >> 1) <= e) ++rr;
    while (((rr * (rr + 1)) >> 1) > e) --rr;
    *r_out = rr;
    *c_out = e - ((rr * (rr + 1)) >> 1);
}

// ---------- L = B^T B + EPS*I : 64x64 register-tiled ----------
__global__ __launch_bounds__(256) void compute_L(const float* __restrict__ B,
                                                 float* __restrict__ L) {
    const int r0 = blockIdx.x * 64, c0 = blockIdx.y * 64;
    const int tx = threadIdx.x & 15, ty = threadIdx.x >> 4;
    __shared__ float Bi[16][64];
    __shared__ float Bj[16][64];
    float acc[4][4] = {};
    for (int k0 = 0; k0 < N; k0 += 16) {
#pragma unroll
        for (int q = 0; q < 4; ++q) {
            const int e = threadIdx.x + q * 256;
            const int kr = e >> 6, cc = e & 63;
            Bi[kr][cc] = B[(k0 + kr) * N + r0 + cc];
            Bj[kr][cc] = B[(k0 + kr) * N + c0 + cc];
        }
        __syncthreads();
#pragma unroll
        for (int kq = 0; kq < 16; ++kq) {
            float a[4], b[4];
#pragma unroll
            for (int q = 0; q < 4; ++q) {
                a[q] = Bi[kq][ty * 4 + q];
                b[q] = Bj[kq][tx * 4 + q];
            }
#pragma unroll
            for (int i = 0; i < 4; ++i)
#pragma unroll
                for (int j = 0; j < 4; ++j) acc[i][j] = fmaf(a[i], b[j], acc[i][j]);
        }
        __syncthreads();
    }
#pragma unroll
    for (int i = 0; i < 4; ++i) {
        const int r = r0 + ty * 4 + i;
        f32x4 v;
#pragma unroll
        for (int j = 0; j < 4; ++j) {
            const int c = c0 + tx * 4 + j;
            v[j] = acc[i][j] + ((r == c) ? EPS : 0.0f);
        }
        *(f32x4*)(&L[r * N + c0 + tx * 4]) = v;
    }
}

// gather: MODE 0/1 from L via idx (+add1 diag); MODE 2 from S slab (lower tri).
// ID=true: idx is identity (zcase) — skip the LDS idx lookup on the load chain.
template <int MODE, bool ID>
__device__ __forceinline__ float gath(const float* __restrict__ L,
                                      const float* __restrict__ S, const short* idx,
                                      int k, bool add1, int gr, int gc) {
    if constexpr (MODE <= 1) {
        if (gr < k && gc < k) {
            float v = ID ? L[gr * N + gc] : L[(int)idx[gr] * N + (int)idx[gc]];
            if (add1 && gr == gc) v += 1.0f;
            return v;
        }
        return (gr == gc) ? 1.0f : 0.0f;
    } else {
        if (gr < k && gc < k) {
            const int r2 = gr > gc ? gr : gc, c2 = gr > gc ? gc : gr;
            return S[r2 * SLD2 + c2];
        }
        return (gr == gc) ? 1.0f : 0.0f;
    }
}

// ---------- 32-col-panel left-looking Cholesky, one barrier pair per panel ----
template <int MODE, bool ID>
__device__ float chol32(char* arena, const float* __restrict__ S,
                        const float* __restrict__ L, const short* idx,
                        int k, int rows, int ncols, bool add1) {
    const int tid = threadIdx.x;
    const int lane = tid & 63, wv = tid >> 6;
    constexpr int scr_off = (MODE == 0) ? SCR0_OFF : (MODE == 1) ? SCR1_OFF : SCR2_OFF;
    constexpr int m_off = (MODE == 0) ? M0_OFF : (MODE == 1) ? M1_OFF : M2_OFF;
    f16* Lh = (f16*)arena;
    f16* Gl = (f16*)(arena + G1_OFF);
    f16* scr = (f16*)(arena + scr_off) + wv * 576;   // per-wave [16][36]
    f16* Mm = (f16*)(arena + m_off);                 // M0 [16][40], M1 at +640
    const int frow = lane & 15, koff = (lane >> 4) * 8;
    const int crow = (lane >> 4) * 4, ccol = lane & 15;
    const f32x4 zz = {0.f, 0.f, 0.f, 0.f};

    float lg2 = 0.0f;

    auto ld_af = [&]() -> f16x8 {                    // zero k-elems 16..31
        if (koff < 16) return *(const f16x8*)(&scr[frow * 36 + koff]);
        f16x8 z = {};
        return z;
    };
    auto scr_st = [&](const f32x4& v) {
#pragma unroll
        for (int q = 0; q < 4; ++q) scr[(crow + q) * 36 + ccol] = (f16)v[q];
    };
    auto factor16 = [&](int rbase, int cbase, f16* mdst) {
        float row[16], w[16];
#pragma unroll
        for (int c = 0; c < 16; ++c) row[c] = (float)scr[frow * 36 + c];
#pragma unroll
        for (int c = 0; c < 16; ++c) w[c] = (c == frow) ? 1.0f : 0.0f;
#pragma unroll
        for (int j = 0; j < 16; ++j) {
            const float piv = rdl(row[j], j);
            lg2 += __log2f(piv);
            const float irs = rsqrtf(piv);
            row[j] *= irs;
            w[j] *= irs;
#pragma unroll
            for (int cc = j + 1; cc < 16; ++cc) {
                const float s2 = rdl(row[j], cc);
                row[cc] = fmaf(-row[j], s2, row[cc]);
                w[cc] = fmaf(-s2, w[j], w[cc]);
            }
        }
        if (lane < 16) {
            f16x8 hv0, hv1;
#pragma unroll
            for (int m2 = 0; m2 < 8; ++m2) {
                hv0[m2] = (f16)row[m2];
                hv1[m2] = (f16)row[8 + m2];
            }
            *(f16x8*)(&Lh[lh_base(rbase + lane) + cbase]) = hv0;
            if (lane >= 8) *(f16x8*)(&Lh[lh_base(rbase + lane) + cbase + 8]) = hv1;
        }
        if (lane < 32) {
#pragma unroll
            for (int i = 0; i < 16; ++i)
                mdst[i * 40 + lane] = (lane < 16) ? (f16)w[i] : (f16)0.0f;
        }
    };
    auto stX = [&](const f32x4& x, int rr0, int cb) {
#pragma unroll
        for (int q = 0; q < 4; ++q) {
            const int gr = rr0 + crow + q;
            const f16 h = (f16)x[q];
            if (MODE == 1 && gr >= SPLIT) Gl[(gr - SPLIT) * GSTR + cb + ccol] = h;
            else Lh[lh_base(gr) + cb + ccol] = h;
        }
    };
    // wave-0 diag gathers (panel-state independent -> prefetchable)
    auto ld_diag = [&](int j0, bool h, f32x4& A, f32x4& B2, f32x4& C2) {
#pragma unroll
        for (int q = 0; q < 4; ++q)
            A[q] = gath<MODE, ID>(L, S, idx, k, add1, j0 + crow + q, j0 + ccol);
        if (!h) {
#pragma unroll
            for (int q = 0; q < 4; ++q) {
                B2[q] = gath<MODE, ID>(L, S, idx, k, add1, j0 + 16 + crow + q, j0 + ccol);
                C2[q] = gath<MODE, ID>(L, S, idx, k, add1, j0 + 16 + crow + q, j0 + 16 + ccol);
            }
        }
    };

    // prefetch panel 0 diag
    f32x4 pg00 = zz, pg10 = zz, pg11 = zz;
    if (wv == 0 && ncols > 0) ld_diag(0, ncols <= 16, pg00, pg10, pg11);

    for (int jb = 0; jb < ncols; jb += 32) {
        const bool half = (ncols - jb) <= 16;
        const int nkk = jb >> 5;                     // jb always mult of 32
        const int ntile = (rows - jb) >> 4;
        const int nbelow = ntile - (half ? 1 : 2);
        const int rb0 = jb + (half ? 16 : 32);

        // state carried across barrier 1 (per-thread regs)
        bool val_[2] = {false, false};
        int r0_[2] = {0, 0};
        f16x8 afs_[2] = {};
        f32x4 s1_[2] = {};

        if (wv == 0) {
            // ---- wave 0: diag 32-block, gathers carried from prefetch
            const f32x4 g00 = pg00, g10 = pg10, g11 = pg11;
            const int bF0 = lh_base(jb + frow) + koff;
            const int bF1 = lh_base(jb + 16 + frow) + koff;
            f32x4 a00 = zz, a10 = zz, a11 = zz;
            for (int c = 0; c < nkk; ++c) {
                const int kk = c << 5;
                const f16x8 F0 = *(const f16x8*)(&Lh[bF0 + kk]);
                a00 = __builtin_amdgcn_mfma_f32_16x16x32_f16(F0, F0, a00, 0, 0, 0);
                if (!half) {
                    const f16x8 F1 = *(const f16x8*)(&Lh[bF1 + kk]);
                    a10 = __builtin_amdgcn_mfma_f32_16x16x32_f16(F1, F0, a10, 0, 0, 0);
                    a11 = __builtin_amdgcn_mfma_f32_16x16x32_f16(F1, F1, a11, 0, 0, 0);
                }
            }
            // issue next panel's diag gathers NOW — they fly under the factor chains
            const int jn = jb + 32;
            if (jn < ncols) ld_diag(jn, (ncols - jn) <= 16, pg00, pg10, pg11);

            f32x4 s00;
#pragma unroll
            for (int q = 0; q < 4; ++q) s00[q] = g00[q] - a00[q];
            scr_st(s00);
            factor16(jb, jb, Mm);                    // diag0 + M0
            if (!half) {
                f32x4 s10;
#pragma unroll
                for (int q = 0; q < 4; ++q) s10[q] = g10[q] - a10[q];
                scr_st(s10);
                const f16x8 af10 = ld_af();
                const f16x8 bM0 = *(const f16x8*)(&Mm[frow * 40 + koff]);
                const f32x4 x10 = __builtin_amdgcn_mfma_f32_16x16x32_f16(af10, bM0, zz, 0, 0, 0);
#pragma unroll
                for (int q = 0; q < 4; ++q)          // publish X10 (always Lh rows)
                    Lh[lh_base(jb + 16 + crow + q) + jb + ccol] = (f16)x10[q];
                scr_st(x10);
                const f16x8 afx = ld_af();           // A-frag == B-frag layout
                const f32x4 pr = __builtin_amdgcn_mfma_f32_16x16x32_f16(afx, afx, zz, 0, 0, 0);
                f32x4 s11;
#pragma unroll
                for (int q = 0; q < 4; ++q) s11[q] = g11[q] - a11[q] - pr[q];
                scr_st(s11);
                factor16(jb + 16, jb + 16, Mm + 640);  // diag1 + M1
            }
        } else {
            // ---- waves 1..15: (a) for owned below-tiles, both column blocks
            bool isg_[2];
            int baseA_[2];
#pragma unroll
            for (int it = 0; it < 2; ++it) {
                const int tb = (wv - 1) + 15 * it;
                val_[it] = tb < nbelow;
                const int rr = rb0 + 16 * (val_[it] ? tb : 0);
                r0_[it] = rr;
                isg_[it] = (MODE == 1) && val_[it] && (rr >= SPLIT);
                baseA_[it] = isg_[it] ? ((rr - SPLIT + frow) * GSTR + koff)
                                      : (lh_base(rr + frow) + koff);
            }
            f32x4 g0_[2] = {zz, zz}, g1_[2] = {zz, zz};
#pragma unroll
            for (int it = 0; it < 2; ++it)
                if (val_[it]) {
#pragma unroll
                    for (int q = 0; q < 4; ++q) {
                        g0_[it][q] = gath<MODE, ID>(L, S, idx, k, add1, r0_[it] + crow + q, jb + ccol);
                        if (!half)
                            g1_[it][q] = gath<MODE, ID>(L, S, idx, k, add1, r0_[it] + crow + q, jb + 16 + ccol);
                    }
                }
            const int bB0 = lh_base(jb + frow) + koff;
            const int bB1 = lh_base(jb + 16 + frow) + koff;
            f32x4 ac0_[2] = {zz, zz}, ac1_[2] = {zz, zz};
            for (int c = 0; c < nkk; ++c) {
                const int kk = c << 5;
                const f16x8 B0 = *(const f16x8*)(&Lh[bB0 + kk]);
                f16x8 B1 = {};
                if (!half) B1 = *(const f16x8*)(&Lh[bB1 + kk]);
#pragma unroll
                for (int it = 0; it < 2; ++it)
                    if (val_[it]) {
                        const f16x8 A = isg_[it] ? *(const f16x8*)(&Gl[baseA_[it] + kk])
                                                 : *(const f16x8*)(&Lh[baseA_[it] + kk]);
                        ac0_[it] = __builtin_amdgcn_mfma_f32_16x16x32_f16(A, B0, ac0_[it], 0, 0, 0);
                        if (!half)
                            ac1_[it] = __builtin_amdgcn_mfma_f32_16x16x32_f16(A, B1, ac1_[it], 0, 0, 0);
                    }
            }
            // pre-barrier staging: S0 -> scr -> A-frag regs; S1 stays in C-frags
#pragma unroll
            for (int it = 0; it < 2; ++it)
                if (val_[it]) {
                    f32x4 s0;
#pragma unroll
                    for (int q = 0; q < 4; ++q) s0[q] = g0_[it][q] - ac0_[it][q];
                    scr_st(s0);
                    afs_[it] = ld_af();
                    if (!half) {
#pragma unroll
                        for (int q = 0; q < 4; ++q) s1_[it][q] = g1_[it][q] - ac1_[it][q];
                    }
                }
        }
        __syncthreads();   // barrier 1: M0/M1, diag factor rows, X10 published

        // ---- (c): all below-tile waves (val_ false on wave 0)
        {
            const f16x8 bM0 = *(const f16x8*)(&Mm[frow * 40 + koff]);
            f16x8 bM1 = {}, bX10 = {};
            if (!half) {
                bM1 = *(const f16x8*)(&Mm[640 + frow * 40 + koff]);
                bX10 = *(const f16x8*)(&Lh[lh_base(jb + 16 + frow) + jb + koff]);
            }
#pragma unroll
            for (int it = 0; it < 2; ++it)
                if (val_[it]) {
                    const f32x4 x0 = __builtin_amdgcn_mfma_f32_16x16x32_f16(afs_[it], bM0, zz, 0, 0, 0);
                    stX(x0, r0_[it], jb);
                    if (!half) {
                        scr_st(x0);
                        const f16x8 afx = ld_af();   // zeroed k>=16 (bX10 k>=16 holds diag1!)
                        const f32x4 pr = __builtin_amdgcn_mfma_f32_16x16x32_f16(afx, bX10, zz, 0, 0, 0);
                        f32x4 s1p;
#pragma unroll
                        for (int q = 0; q < 4; ++q) s1p[q] = s1_[it][q] - pr[q];
                        scr_st(s1p);
                        const f16x8 af1 = ld_af();
                        const f32x4 x1 = __builtin_amdgcn_mfma_f32_16x16x32_f16(af1, bM1, zz, 0, 0, 0);
                        stX(x1, r0_[it], jb + 16);
                    }
                }
        }
        __syncthreads();   // barrier 2: factor cols jb..jb+31 published
    }
    return lg2;
}

// ---------- S = A22 - G·G^T, G in LDS; S (fp32) streamed to global ----------
template <bool ID>
__device__ void schur32(char* arena, float* __restrict__ S,
                        const float* __restrict__ L, const short* idx,
                        int k, int k2p, bool add1) {
    const int tid = threadIdx.x;
    const int lane = tid & 63, wv = tid >> 6;
    const f16* Gl = (const f16*)(arena + G1_OFF);
    const int frow = lane & 15, koff = (lane >> 4) * 8;
    const int crow = (lane >> 4) * 4, ccol = lane & 15;
    const int nt2 = k2p >> 4, TT = (nt2 * (nt2 + 1)) >> 1;
    for (int e = wv; e < TT; e += NW) {
        int R, C;
        tri_map(e, &R, &C);
        const int r0 = R << 4, c0 = C << 4;
        f32x4 g;
#pragma unroll
        for (int q = 0; q < 4; ++q) {
            const int gr = SPLIT + r0 + crow + q, gc = SPLIT + c0 + ccol;
            float v;
            if (gr < k && gc < k) {
                v = ID ? L[gr * N + gc] : L[(int)idx[gr] * N + (int)idx[gc]];
                if (add1 && gr == gc) v += 1.0f;
            } else v = (gr == gc) ? 1.0f : 0.0f;
            g[q] = v;
        }
        const int ba = (r0 + frow) * GSTR + koff, bb = (c0 + frow) * GSTR + koff;
        f32x4 acc = {0.f, 0.f, 0.f, 0.f};
#pragma unroll
        for (int c = 0; c < SPLIT / 32; ++c) {       // 5 aligned chunks
            const f16x8 A = *(const f16x8*)(&Gl[ba + (c << 5)]);
            const f16x8 B = *(const f16x8*)(&Gl[bb + (c << 5)]);
            acc = __builtin_amdgcn_mfma_f32_16x16x32_f16(A, B, acc, 0, 0, 0);
        }
#pragma unroll
        for (int q = 0; q < 4; ++q)
            S[(r0 + crow + q) * SLD2 + c0 + ccol] = g[q] - acc[q];
    }
}

// ---------- one block per batch item; block BATCH = logdet(L+I) ----------
// launch_bounds 2nd arg = min BLOCKS/CU (CUDA semantics on hipcc — R14's spill
// disaster at (TPB,4): cap 64 VGPR). (TPB,1) lifts the cap to the geometric 128.
__global__ __launch_bounds__(TPB, 1) void chol_all(const int* __restrict__ x,
                                                   const float* __restrict__ L,
                                                   char* __restrict__ slabs, int nslabs,
                                                   float* __restrict__ logs) {
    const int b = blockIdx.x;
    const int tid = threadIdx.x;
    const int lane = tid & 63, wv = tid >> 6;
    __shared__ __align__(16) char arena[ARENA_SZ];
    __shared__ short idx[N];
    __shared__ int wcnt[NW];

    const bool zc = (b == BATCH);
    const bool inx = tid < N;
    const bool act = zc ? inx : (inx && x[(size_t)b * N + tid] != 0);
    const unsigned long long m = __ballot(act);
    if (lane == 0) wcnt[wv] = __popcll(m);
    __syncthreads();
    int off = 0, ktot = 0;
    for (int q = 0; q < NW; ++q) {
        if (q < wv) off += wcnt[q];
        ktot += wcnt[q];
    }
    if (act) idx[off + __popcll(m & ((1ULL << lane) - 1ULL))] = (short)tid;
    __syncthreads();

    const int k = ktot;
    const int kp = (k + 15) & ~15;

    float lg2;
    if (!zc && kp <= KP) {
        lg2 = chol32<0, false>(arena, nullptr, L, idx, k, kp, kp, false);
    } else {
        const int si = zc ? 0 : (nslabs > 1 ? 1 + (b % (nslabs - 1)) : 0);
        float* S = (float*)(slabs + (size_t)si * SLAB_BYTES);
        const int k2 = k - SPLIT, k2p = kp - SPLIT;
        if (zc) {
            lg2 = chol32<1, true>(arena, nullptr, L, idx, k, kp, SPLIT, true);
            schur32<true>(arena, S, L, idx, k, k2p, true);
            __syncthreads();   // all G reads done before stage2 overwrites the arena
            lg2 += chol32<2, true>(arena, S, L, idx, k2, k2p, k2p, false);
        } else {
            lg2 = chol32<1, false>(arena, nullptr, L, idx, k, kp, SPLIT, false);
            schur32<false>(arena, S, L, idx, k, k2p, false);
            __syncthreads();
            lg2 += chol32<2, false>(arena, S, L, idx, k2, k2p, k2p, false);
        }
    }
    if (tid == 0) logs[b] = lg2 * LN2;
}

__global__ void finalize(const float* __restrict__ logs, float* __restrict__ out) {
    const int i = threadIdx.x;
    out[i] = logs[i] - logs[BATCH];
}

extern "C" void kernel_launch(void* const* d_in, const int* in_sizes, int n_in,
                              void* d_out, int out_size, void* d_ws, size_t ws_size,
                              hipStream_t stream) {
    const int* x = (const int*)d_in[0];
    const float* B = (const float*)d_in[1];
    float* out = (float*)d_out;

    char* ws = (char*)d_ws;
    const size_t L_bytes = (size_t)N * N * 4;  // 1 MB
    float* L = (float*)ws;
    float* logs = (float*)(ws + L_bytes);
    const size_t head = L_bytes + 4096;
    char* slabs = ws + head;
    int nslabs = (ws_size > head) ? (int)((ws_size - head) / SLAB_BYTES) : 1;
    if (nslabs < 1) nslabs = 1;
    if (nslabs > 9) nslabs = 9;

    compute_L<<<dim3(8, 8), 256, 0, stream>>>(B, L);
    chol_all<<<BATCH + 1, TPB, 0, stream>>>(x, L, slabs, nslabs, logs);
    finalize<<<1, BATCH, 0, stream>>>(logs, out);
}